// Round 8
// baseline (283.232 us; speedup 1.0000x reference)
//
#include <hip/hip_runtime.h>

// KrausRK4 via bf16 MFMA, r8: in-register chaining, assemble() rebuilt from
// session-verified primitives only (bf16rne packing + __shfl_xor(32) + select)
// — no inline asm, no permlane builtin. 10 barrier phases, LDS 4 x 8KB.
// phys(row, cbyte) = row*128 + (((cbyte>>4) ^ ((row>>3)&7))<<4) + (cbyte&15)

typedef __attribute__((ext_vector_type(16))) float f32x16;
typedef __attribute__((ext_vector_type(8))) __bf16 bf16x8;

#define MATB 8192

__device__ __forceinline__ unsigned short bf16rne(float x) {
  unsigned u = __builtin_bit_cast(unsigned, x);
  return (unsigned short)((u + 0x7FFFu + ((u >> 16) & 1u)) >> 16);
}
__device__ __forceinline__ float bflo(unsigned u) {
  return __builtin_bit_cast(float, u << 16);
}
__device__ __forceinline__ float bfhi(unsigned u) {
  return __builtin_bit_cast(float, u & 0xFFFF0000u);
}
__device__ __forceinline__ unsigned pk2(float lo, float hi) {
  return (unsigned)bf16rne(lo) | ((unsigned)bf16rne(hi) << 16);
}

union U4 { uint4 u; bf16x8 h; };

// Build the step-s operand fragment (k = s*16 + lh*8 + i) from first-product
// C-tiles. Needs (derived from C/D layout, re-verified r7 post-mortem):
//   lower-half lanes: elems0-3 = own t[b8+0..3], elems4-7 = partner t[b8+0..3]
//   upper-half lanes: elems0-3 = partner t[b8+4..7], elems4-7 = own t[b8+4..7]
// partner = lane ^ 32.
__device__ __forceinline__ bf16x8 assemble(const f32x16& t, int b8, int lh) {
  unsigned u0 = pk2(t[b8 + 0], t[b8 + 1]);
  unsigned u1 = pk2(t[b8 + 2], t[b8 + 3]);
  unsigned w0 = pk2(t[b8 + 4], t[b8 + 5]);
  unsigned w1 = pk2(t[b8 + 6], t[b8 + 7]);
  unsigned su0 = __shfl_xor(u0, 32);
  unsigned su1 = __shfl_xor(u1, 32);
  unsigned sw0 = __shfl_xor(w0, 32);
  unsigned sw1 = __shfl_xor(w1, 32);
  U4 r;
  r.u = make_uint4(lh ? sw0 : u0, lh ? sw1 : u1,
                   lh ? w0 : su0, lh ? w1 : su1);
  return r.h;
}

// first product: acc += P @ Q^T, P = LDS matrix rows (swizzled), Q = op frags
__device__ __forceinline__ void mm4_lg(f32x16& acc, const char* ldsP, int vp,
                                       int lh, const char* __restrict__ gQ) {
#pragma unroll
  for (int s = 0; s < 4; ++s) {
    bf16x8 a = *(const bf16x8*)(ldsP + (((2 * s + lh) ^ vp) << 4));
    bf16x8 b = *(const bf16x8*)(gQ + s * 1024);
    acc = __builtin_amdgcn_mfma_f32_32x32x16_bf16(a, b, acc, 0, 0, 0);
  }
}

// second product, P = op frags (global), Q = assembled: acc += op2 @ T^T (hat)
__device__ __forceinline__ void secondGP(f32x16& acc, const char* __restrict__ gP,
                                         const f32x16& t0, const f32x16& t1,
                                         int lh) {
#pragma unroll
  for (int s = 0; s < 4; ++s) {
    bf16x8 q = assemble((s < 2) ? t0 : t1, (s & 1) * 8, lh);
    bf16x8 p = *(const bf16x8*)(gP + s * 1024);
    acc = __builtin_amdgcn_mfma_f32_32x32x16_bf16(p, q, acc, 0, 0, 0);
  }
}
// second product, P = assembled, Q = op frags (global): acc += T @ op2^T (plain)
__device__ __forceinline__ void secondGQ(f32x16& acc, const f32x16& t0,
                                         const f32x16& t1,
                                         const char* __restrict__ gQ, int lh) {
#pragma unroll
  for (int s = 0; s < 4; ++s) {
    bf16x8 p = assemble((s < 2) ? t0 : t1, (s & 1) * 8, lh);
    bf16x8 q = *(const bf16x8*)(gQ + s * 1024);
    acc = __builtin_amdgcn_mfma_f32_32x32x16_bf16(p, q, acc, 0, 0, 0);
  }
}

// write 32x32 C-tile (row-major, swizzled): row = ti*32+4lh+(r&3)+8(r>>2)
__device__ __forceinline__ void wtile(char* base, int ti, int slotc, int coff,
                                      int lh, const f32x16& v) {
#pragma unroll
  for (int r = 0; r < 16; ++r) {
    int row = ti * 32 + 4 * lh + (r & 3) + 8 * (r >> 2);
    int ps = (slotc ^ ((4 * ti + (r >> 2)) & 7)) << 4;
    *(unsigned short*)(base + row * 128 + ps + coff) = bf16rne(v[r]);
  }
}
__device__ __forceinline__ void wtile_rmw(char* base, int ti, int slotc, int coff,
                                          int lh, const f32x16& v, float s) {
#pragma unroll
  for (int r = 0; r < 16; ++r) {
    int row = ti * 32 + 4 * lh + (r & 3) + 8 * (r >> 2);
    int ps = (slotc ^ ((4 * ti + (r >> 2)) & 7)) << 4;
    unsigned short* p = (unsigned short*)(base + row * 128 + ps + coff);
    float old = bflo((unsigned)*p);
    *p = bf16rne(old + s * v[r]);
  }
}

// D = A + s*B elementwise on raw swizzled dwords (2048 per matrix)
__device__ __forceinline__ void axpy(char* D, const char* A, float s,
                                     const char* B, int tid) {
#pragma unroll
  for (int j = 0; j < 8; ++j) {
    int off = (tid + 256 * j) * 4;
    unsigned a = *(const unsigned*)(A + off);
    unsigned b = *(const unsigned*)(B + off);
    float lo = bflo(a) + s * bflo(b);
    float hi = bfhi(a) + s * bfhi(b);
    *(unsigned*)(D + off) = (unsigned)bf16rne(lo) | ((unsigned)bf16rne(hi) << 16);
  }
}

// ---------------- Um1 = U1 @ inv(Um), fp32 Gauss-Jordan, no pivot -----------
__global__ __launch_bounds__(256) void kraus_invert(
    const float* __restrict__ U1, const float* __restrict__ Um,
    float* __restrict__ Um1) {
  __shared__ float M[64][66];
  __shared__ float X[64][66];
  int tid = threadIdx.x;
#pragma unroll
  for (int it = 0; it < 16; ++it) {
    int idx = tid + 256 * it;
    int r = idx >> 6, c = idx & 63;
    M[r][c] = Um[idx];
    X[r][c] = (r == c) ? 1.0f : 0.0f;
  }
  __syncthreads();
  for (int k = 0; k < 64; ++k) {
    if (tid < 64) {
      float ip = 1.0f / M[k][k];
      M[k][tid] *= ip;
      X[k][tid] *= ip;
    }
    __syncthreads();
    int r = tid & 63, q = tid >> 6;
    float f = M[r][k];
    __syncthreads();
    if (r != k) {
#pragma unroll
      for (int cc = 0; cc < 16; ++cc) {
        int c = q * 16 + cc;
        M[r][c] -= f * M[k][c];
        X[r][c] -= f * X[k][c];
      }
    }
    __syncthreads();
  }
  for (int it = 0; it < 16; ++it) {
    int idx = tid + 256 * it;
    int i = idx >> 6, j = idx & 63;
    float s = 0.0f;
#pragma unroll 4
    for (int k = 0; k < 64; ++k) s += U1[i * 64 + k] * X[k][j];
    Um1[idx] = s;
  }
}

// ---------------- prepack: 15 operators -> bf16 fragment-major in ws --------
// op order: 0=U1 1=Um 2=Um1 3..6=Ls0 7..10=Lsmid 11..14=Ls1
__global__ __launch_bounds__(256) void kraus_prepack(
    const float* __restrict__ U1, const float* __restrict__ Um,
    const float* __restrict__ Ls0, const float* __restrict__ Lsmid,
    const float* __restrict__ Ls1, float* __restrict__ ws) {
  const float* Um1 = ws;
  unsigned short* dst = (unsigned short*)((char*)ws + 16384);
  int o = blockIdx.x;
  const float* s;
  if (o == 0) s = U1;
  else if (o == 1) s = Um;
  else if (o == 2) s = Um1;
  else if (o < 7) s = Ls0 + (o - 3) * 4096;
  else if (o < 11) s = Lsmid + (o - 7) * 4096;
  else s = Ls1 + (o - 11) * 4096;
  unsigned short* d = dst + o * 4096;
  int tid = threadIdx.x;
#pragma unroll
  for (int j = 0; j < 16; ++j) {
    int idx = tid + 256 * j;
    int f = idx >> 9, l = (idx >> 3) & 63, i = idx & 7;
    int t = f >> 2, ss = f & 3;
    int R = t * 32 + (l & 31);
    int C = ss * 16 + (l >> 5) * 8 + i;
    d[idx] = bf16rne(s[R * 64 + C]);
  }
}

// ---------------- main kernel: one block per batch item, 10 phases ----------
__global__ __launch_bounds__(256, 2) void kraus_main(
    const float* __restrict__ rho0g, const float* __restrict__ dtp,
    const char* __restrict__ gfrag, float* __restrict__ outg) {
  __shared__ __align__(16) char lds[4 * MATB];   // 32768 B
  char* S0 = lds;              // hat(rho0) -> hat(J2)
  char* S1 = S0 + MATB;        // hat(J0) -> hat(P) -> hat(rho4)
  char* S2 = S1 + MATB;        // hat(T) -> hat(S) -> hat(J3)
  char* S3 = S2 + MATB;        // hat(rho2) -> hat(rho3)

  const int tid = threadIdx.x;
  const int l = tid & 63, w = tid >> 6;
  const int ti = w >> 1, tj = w & 1;
  const int l31 = l & 31, lh = l >> 5;
  const int row0 = l31 * 128;                // P row-block a=0
  const int row1 = (32 + l31) * 128;         // P row-block a=1
  const int vk0 = l31 >> 3;                  // swizzle key a=0
  const int vk1 = 4 + (l31 >> 3);            // swizzle key a=1
  const int slotc = 4 * tj + (l31 >> 3), coff = (l31 & 7) * 2;
  const float dt = dtp[0];
  const size_t b = blockIdx.x;

  auto GF = [&](int op, int blk) {
    return gfrag + op * 8192 + blk * 4096 + l * 16;
  };
  // first products: t0/t1 = tiles (a=0/1, blk) of T = op@X, X hat in LDS
  auto firsts = [&](const char* X, int op, int blk, f32x16& t0, f32x16& t1) {
    mm4_lg(t0, X + row0, vk0, lh, GF(op, blk));
    mm4_lg(t1, X + row1, vk1, lh, GF(op, blk));
  };
  // acc += plain (op1 @ X @ op2^T)[ti][tj]
  auto sandPlain = [&](f32x16& acc, const char* X, int op1, int op2) {
    f32x16 t0 = {}, t1 = {};
    firsts(X, op1, ti, t0, t1);
    secondGQ(acc, t0, t1, GF(op2, tj), lh);
  };
  // acc += hat(op1 @ X @ op2^T)[ti][tj]
  auto sandHat = [&](f32x16& acc, const char* X, int op1, int op2) {
    f32x16 t0 = {}, t1 = {};
    firsts(X, op1, tj, t0, t1);
    secondGP(acc, GF(op2, ti), t0, t1, lh);
  };
  auto WT = [&](char* dst, const f32x16& v) { wtile(dst, ti, slotc, coff, lh, v); };

  // ph1: stage hat(rho0) -> S0 (swizzled)
  {
    const float* src = rho0g + b * 4096 + tid * 16;
    float vals[16];
#pragma unroll
    for (int q = 0; q < 4; ++q) {
      float4 f = *(const float4*)(src + q * 4);
      vals[q * 4 + 0] = f.x; vals[q * 4 + 1] = f.y;
      vals[q * 4 + 2] = f.z; vals[q * 4 + 3] = f.w;
    }
    int r = tid >> 2, c0 = (tid & 3) * 16;
    int sr = r >> 3, cr = (r & 7) * 2;
#pragma unroll
    for (int u = 0; u < 16; ++u) {
      int row = c0 + u;
      int ps = (sr ^ ((row >> 3) & 7)) << 4;
      *(unsigned short*)(S0 + row * 128 + ps + cr) = bf16rne(vals[u]);
    }
  }
  __syncthreads();

  f32x16 outacc = {};

  // ph2: hat(J0) = sum_k hat(L0k @ rho0 @ L0k^T) [reads S0] -> S1
  {
    f32x16 J = {};
#pragma unroll
    for (int k = 0; k < 4; ++k) sandHat(J, S0, 3 + k, 3 + k);
    WT(S1, J);
  }
  __syncthreads();

  // ph3: out += dt/6 * sand(U1, J0) [reads S1]; hat(T) = S0 + 0.5dt*S1 -> S2
  {
    f32x16 a = {};
    sandPlain(a, S1, 0, 0);
    outacc += (dt / 6.f) * a;
    axpy(S2, S0, 0.5f * dt, S1, tid);
  }
  __syncthreads();

  // ph4: out += sand(U1, rho0); hat(P) -> S1 (J0 dead); hat(rho2) -> S3
  {
    { f32x16 a = {}; sandPlain(a, S0, 0, 0); outacc += a; }
    { f32x16 a = {}; sandHat(a, S0, 0, 0); WT(S1, a); }   // hat(P)
    { f32x16 a = {}; sandHat(a, S2, 1, 1); WT(S3, a); }   // hat(rho2)
  }
  __syncthreads();

  // ph5: hat(S) = hat(sand(Um, rho0)) [reads S0] -> S2 (T dead)
  {
    f32x16 a = {};
    sandHat(a, S0, 1, 1);
    WT(S2, a);
  }
  __syncthreads();

  // ph6: hat(J2) [reads S3 = hat(rho2)] -> S0 (rho0 dead)
  {
    f32x16 J = {};
#pragma unroll
    for (int k = 0; k < 4; ++k) sandHat(J, S3, 7 + k, 7 + k);
    WT(S0, J);
  }
  __syncthreads();

  // ph7: hat(rho3) = hat(S) + 0.5dt*hat(J2) -> S3 (rho2 dead)
  axpy(S3, S2, 0.5f * dt, S0, tid);
  __syncthreads();

  // ph8: hat(J3) [reads S3] -> S2 (S dead)
  {
    f32x16 J = {};
#pragma unroll
    for (int k = 0; k < 4; ++k) sandHat(J, S3, 7 + k, 7 + k);
    WT(S2, J);
  }
  __syncthreads();

  // ph9: out += dt/3*(sand(Um1,J2) + sand(Um1,J3));
  //      hat(rho4) = hat(P) + dt*hat(sand(Um1,J3)) via rmw on S1
  {
    { f32x16 a = {}; sandPlain(a, S0, 2, 2); outacc += (dt / 3.f) * a; }
    { f32x16 a = {}; sandPlain(a, S2, 2, 2); outacc += (dt / 3.f) * a; }
    { f32x16 a = {}; sandHat(a, S2, 2, 2);
      wtile_rmw(S1, ti, slotc, coff, lh, a, dt); }
  }
  __syncthreads();

  // ph10: out += dt/6 * jump(Ls1, rho4) [reads S1 = hat(rho4)], plain
  {
    f32x16 J = {};
#pragma unroll
    for (int k = 0; k < 4; ++k) sandPlain(J, S1, 11 + k, 11 + k);
    outacc += (dt / 6.f) * J;
  }

  // store fp32 output tile
  {
    float* op = outg + b * 4096 + (size_t)(ti * 32 + lh * 4) * 64 + tj * 32 + l31;
#pragma unroll
    for (int r = 0; r < 16; ++r) {
      int row = (r & 3) + 8 * (r >> 2);
      op[row * 64] = outacc[r];
    }
  }
}

extern "C" void kernel_launch(void* const* d_in, const int* in_sizes, int n_in,
                              void* d_out, int out_size, void* d_ws, size_t ws_size,
                              hipStream_t stream) {
  const float* rho0 = (const float*)d_in[0];
  const float* U1 = (const float*)d_in[1];
  const float* Um = (const float*)d_in[2];
  const float* Ls0 = (const float*)d_in[3];
  const float* Lsmid = (const float*)d_in[4];
  const float* Ls1 = (const float*)d_in[5];
  const float* dtp = (const float*)d_in[6];
  float* out = (float*)d_out;
  float* ws = (float*)d_ws;   // [0,16KB): Um1 fp32; [16KB,136KB): bf16 frags

  const int B = in_sizes[0] >> 12;

  kraus_invert<<<1, 256, 0, stream>>>(U1, Um, ws);
  kraus_prepack<<<15, 256, 0, stream>>>(U1, Um, Ls0, Lsmid, Ls1, ws);
  kraus_main<<<B, 256, 0, stream>>>(rho0, dtp, (const char*)d_ws + 16384, out);
}